// Round 1
// baseline (1551.669 us; speedup 1.0000x reference)
//
#include <hip/hip_runtime.h>
#include <math.h>

#define NB 16
#define C_IN 64
#define C_OUT 64
#define HH 128
#define WW 128
#define MAX_SHIFT 4.0f

#define TS 32          // output tile side
#define CI_G 16        // input channels per LDS group
#define PTS (TS + 2)   // 34
#define CO_CHUNK 16

#define W_STRIDE_CO (192 * 9)   // weight stride per output channel
#define W_STRIDE_P  (64 * 9)    // weight stride per power block

// ---------------- pass 1: per-channel bilinear shift into workspace ----------
__global__ void shift_kernel(const float* __restrict__ x,
                             const float* __restrict__ shifts,
                             float* __restrict__ xs) {
    int idx = blockIdx.x * blockDim.x + threadIdx.x;   // < 2^24
    int j = idx & (WW - 1);
    int i = (idx >> 7) & (HH - 1);
    int c = (idx >> 14) & (C_IN - 1);

    float sx = shifts[2 * c] * MAX_SHIFT;      // width shift
    float sy = shifts[2 * c + 1] * MAX_SHIFT;  // height shift
    float fx0 = floorf(sx), fy0 = floorf(sy);
    int dx0 = (int)fx0, dy0 = (int)fy0;
    float fx = sx - fx0, fy = sy - fy0;

    int y0 = i + dy0, y1 = y0 + 1;
    int x0 = j + dx0, x1 = x0 + 1;

    const float* xb = x + (idx & ~(HH * WW - 1));  // base of this (n,c) plane
    float v00 = (y0 >= 0 && y0 < HH && x0 >= 0 && x0 < WW) ? xb[y0 * WW + x0] : 0.f;
    float v01 = (y0 >= 0 && y0 < HH && x1 >= 0 && x1 < WW) ? xb[y0 * WW + x1] : 0.f;
    float v10 = (y1 >= 0 && y1 < HH && x0 >= 0 && x0 < WW) ? xb[y1 * WW + x0] : 0.f;
    float v11 = (y1 >= 0 && y1 < HH && x1 >= 0 && x1 < WW) ? xb[y1 * WW + x1] : 0.f;

    xs[idx] = (1.f - fy) * ((1.f - fx) * v00 + fx * v01)
            + fy * ((1.f - fx) * v10 + fx * v11);
}

// ---------------- pass 2: direct conv over (xs, xs^2, xs^3) ------------------
template <bool USE_WS>
__global__ __launch_bounds__(256)
void conv_kernel(const float* __restrict__ src,     // xs (if USE_WS) else raw x
                 const float* __restrict__ shifts,
                 const float* __restrict__ weight,  // [64][192][3][3]
                 const float* __restrict__ bias,
                 float* __restrict__ out) {
    __shared__ float tile[CI_G][PTS][PTS];
    __shared__ float s_fx[C_IN], s_fy[C_IN];
    __shared__ int s_dx0[C_IN], s_dy0[C_IN];

    int bid = blockIdx.x;            // n(16) x ti(4) x tj(4)
    int tj = bid & 3;
    int ti = (bid >> 2) & 3;
    int n  = bid >> 4;
    int i0 = ti * TS, j0 = tj * TS;

    int tid = threadIdx.x;
    int tx = tid & 31;               // j within tile
    int ty = tid >> 5;               // i base (0..7); pixels at ty + k*8

    if (!USE_WS) {
        if (tid < C_IN) {
            float sx = shifts[2 * tid] * MAX_SHIFT;
            float sy = shifts[2 * tid + 1] * MAX_SHIFT;
            float fx0 = floorf(sx), fy0 = floorf(sy);
            s_dx0[tid] = (int)fx0; s_dy0[tid] = (int)fy0;
            s_fx[tid] = sx - fx0;  s_fy[tid] = sy - fy0;
        }
        __syncthreads();
    }

    const float* xn = src + n * (C_IN * HH * WW);

    for (int cc = 0; cc < C_OUT / CO_CHUNK; ++cc) {
        float acc[CO_CHUNK][4];
        #pragma unroll
        for (int co = 0; co < CO_CHUNK; ++co) {
            float b = bias[cc * CO_CHUNK + co];
            #pragma unroll
            for (int k = 0; k < 4; ++k) acc[co][k] = b;
        }

        for (int cg = 0; cg < C_IN / CI_G; ++cg) {
            __syncthreads();
            // stage CI_G channels of the (34x34) input tile into LDS
            for (int e = tid; e < CI_G * PTS * PTS; e += 256) {
                int cl  = e / (PTS * PTS);
                int rem = e - cl * (PTS * PTS);
                int y   = rem / PTS;
                int xq  = rem - y * PTS;
                int gi = i0 - 1 + y, gj = j0 - 1 + xq;
                int c = cg * CI_G + cl;
                float v = 0.f;
                if (gi >= 0 && gi < HH && gj >= 0 && gj < WW) {
                    if (USE_WS) {
                        v = src[((n * C_IN + c) * HH + gi) * WW + gj];
                    } else {
                        int y0 = gi + s_dy0[c], y1 = y0 + 1;
                        int x0 = gj + s_dx0[c], x1 = x0 + 1;
                        float fx = s_fx[c], fy = s_fy[c];
                        const float* xp = xn + c * HH * WW;
                        float v00 = (y0 >= 0 && y0 < HH && x0 >= 0 && x0 < WW) ? xp[y0 * WW + x0] : 0.f;
                        float v01 = (y0 >= 0 && y0 < HH && x1 >= 0 && x1 < WW) ? xp[y0 * WW + x1] : 0.f;
                        float v10 = (y1 >= 0 && y1 < HH && x0 >= 0 && x0 < WW) ? xp[y1 * WW + x0] : 0.f;
                        float v11 = (y1 >= 0 && y1 < HH && x1 >= 0 && x1 < WW) ? xp[y1 * WW + x1] : 0.f;
                        v = (1.f - fy) * ((1.f - fx) * v00 + fx * v01)
                          + fy * ((1.f - fx) * v10 + fx * v11);
                    }
                }
                tile[cl][y][xq] = v;
            }
            __syncthreads();

            #pragma unroll 1
            for (int cl = 0; cl < CI_G; ++cl) {
                int ci = cg * CI_G + cl;
                const float* wp = weight + (cc * CO_CHUNK) * W_STRIDE_CO + ci * 9;
                #pragma unroll
                for (int ky = 0; ky < 3; ++ky) {
                    #pragma unroll
                    for (int kx = 0; kx < 3; ++kx) {
                        int tap = ky * 3 + kx;
                        float v1[4], v2[4], v3[4];
                        #pragma unroll
                        for (int k = 0; k < 4; ++k) {
                            float t = tile[cl][ty + k * 8 + ky][tx + kx];
                            v1[k] = t;
                            v2[k] = t * t;
                            v3[k] = v2[k] * t;
                        }
                        #pragma unroll
                        for (int co = 0; co < CO_CHUNK; ++co) {
                            float w1 = wp[co * W_STRIDE_CO + 0 * W_STRIDE_P + tap];
                            float w2 = wp[co * W_STRIDE_CO + 1 * W_STRIDE_P + tap];
                            float w3 = wp[co * W_STRIDE_CO + 2 * W_STRIDE_P + tap];
                            #pragma unroll
                            for (int k = 0; k < 4; ++k) {
                                acc[co][k] += w1 * v1[k];
                                acc[co][k] += w2 * v2[k];
                                acc[co][k] += w3 * v3[k];
                            }
                        }
                    }
                }
            }
        }

        // store this co chunk
        #pragma unroll
        for (int co = 0; co < CO_CHUNK; ++co) {
            int oc = cc * CO_CHUNK + co;
            #pragma unroll
            for (int k = 0; k < 4; ++k) {
                int i = i0 + ty + k * 8;
                out[((n * C_OUT + oc) * HH + i) * WW + (j0 + tx)] = acc[co][k];
            }
        }
    }
}

extern "C" void kernel_launch(void* const* d_in, const int* in_sizes, int n_in,
                              void* d_out, int out_size, void* d_ws, size_t ws_size,
                              hipStream_t stream) {
    const float* x      = (const float*)d_in[0];
    const float* weight = (const float*)d_in[1];
    const float* bias   = (const float*)d_in[2];
    const float* shifts = (const float*)d_in[3];
    float* out = (float*)d_out;

    const size_t xs_bytes = (size_t)NB * C_IN * HH * WW * sizeof(float); // 64 MiB

    if (ws_size >= xs_bytes) {
        float* xs = (float*)d_ws;
        shift_kernel<<<(NB * C_IN * HH * WW) / 256, 256, 0, stream>>>(x, shifts, xs);
        conv_kernel<true><<<NB * 4 * 4, 256, 0, stream>>>(xs, shifts, weight, bias, out);
    } else {
        conv_kernel<false><<<NB * 4 * 4, 256, 0, stream>>>(x, shifts, weight, bias, out);
    }
}

// Round 3
// 146.089 us; speedup vs baseline: 10.6214x; 10.6214x over previous
//
#include <hip/hip_runtime.h>
#include <hip/hip_bf16.h>
#include <math.h>

#define NB 16
#define C_IN 64
#define C_OUT 64
#define HH 128
#define WW 128
#define MAX_SHIFT 4.0f

typedef __attribute__((ext_vector_type(8))) short bf16x8;
typedef __attribute__((ext_vector_type(4))) float f32x4;
typedef __attribute__((ext_vector_type(4))) unsigned int u32x4;

// round-to-nearest-even bf16 from float, as raw u16
__device__ inline unsigned short bf16_rne(float f) {
    unsigned u = __builtin_bit_cast(unsigned, f);
    u += 0x7fffu + ((u >> 16) & 1u);
    return (unsigned short)(u >> 16);
}
// pack two floats (lo, hi) into one u32 of 2x bf16 (RNE)
__device__ inline unsigned pack_bf16x2(float lo, float hi) {
    unsigned ul = __builtin_bit_cast(unsigned, lo);
    unsigned uh = __builtin_bit_cast(unsigned, hi);
    ul += 0x7fffu + ((ul >> 16) & 1u);
    uh += 0x7fffu + ((uh >> 16) & 1u);
    return (ul >> 16) | (uh & 0xffff0000u);
}

// ---- MFMA conv tile geometry ----
#define TH 16
#define TW 32
#define PR (TH + 2)     // 18
#define PC (TW + 2)     // 34
#define NPX (PR * PC)   // 612
#define CHP 40          // padded channel stride in bf16 (80 B, 16B-aligned)

// ============ weight prep: [kg2][p3][t9][mf4][lane64][e8] bf16 ============
__global__ void prep_w(const float* __restrict__ w, unsigned short* __restrict__ wbuf) {
    int id = blockIdx.x * 256 + threadIdx.x;   // < 110592
    int e = id & 7;
    int l = (id >> 3) & 63;
    int frag = id >> 9;            // 0..215
    int mf = frag & 3;
    int f2 = frag >> 2;            // 0..53
    int t = f2 % 9;
    int f3 = f2 / 9;               // 0..5
    int p = f3 % 3;
    int kg = f3 / 3;
    int co = mf * 16 + (l & 15);
    int ci = kg * 32 + (l >> 4) * 8 + e;            // 0..63
    float v = w[(co * 192 + p * 64 + ci) * 9 + t];
    wbuf[id] = bf16_rne(v);
}

// ============ MFMA implicit-GEMM conv ============
__global__ __launch_bounds__(256, 2)
void conv_mfma(const float* __restrict__ x,
               const float* __restrict__ shifts,
               const unsigned short* __restrict__ wbuf,
               const float* __restrict__ bias,
               float* __restrict__ out) {
    __shared__ unsigned short tile[NPX * CHP];      // 48960 B
    __shared__ float s_fx[C_IN], s_fy[C_IN];
    __shared__ int s_dx[C_IN], s_dy[C_IN];

    // bijective XCD swizzle: 512 blocks, 8 XCDs, 64 blocks each -> 2 images/XCD
    int bid = blockIdx.x;
    int wg = (bid & 7) * 64 + (bid >> 3);
    int n  = wg >> 5;
    int t5 = wg & 31;
    int i0 = (t5 >> 2) * TH;
    int j0 = (t5 & 3) * TW;

    int tid = threadIdx.x;
    int l  = tid & 63;
    int wv = tid >> 6;              // wave 0..3
    int lm = l & 15;                // n / m low index
    int lg = l >> 4;                // k-group 0..3

    if (tid < C_IN) {
        float sx = shifts[2 * tid] * MAX_SHIFT;
        float sy = shifts[2 * tid + 1] * MAX_SHIFT;
        float fx0 = floorf(sx), fy0 = floorf(sy);
        s_dx[tid] = (int)fx0; s_dy[tid] = (int)fy0;
        s_fx[tid] = sx - fx0;  s_fy[tid] = sy - fy0;
    }

    // acc init with bias
    f32x4 acc[4][8];
    #pragma unroll
    for (int mf = 0; mf < 4; ++mf) {
        #pragma unroll
        for (int r = 0; r < 4; ++r) {
            float b = bias[mf * 16 + lg * 4 + r];
            #pragma unroll
            for (int nf = 0; nf < 8; ++nf) acc[mf][nf][r] = b;
        }
    }

    const float* xn = x + n * (C_IN * HH * WW);
    const char* ldsb = (const char*)tile;
    // per-lane LDS byte base: pixel (row = wv*4, col = lm), k-block lg
    int lds_base = ((wv * 4) * PC + lm) * (CHP * 2) + lg * 16;

    #pragma unroll 1
    for (int kg = 0; kg < 2; ++kg) {
        __syncthreads();
        // ---- stage: 18x34 halo x 32 channels, bilinear-shifted, bf16, [px][ch] ----
        for (int e = tid; e < NPX * 32; e += 256) {
            int cl = e / NPX;
            int px = e - cl * NPX;
            int r  = px / PC;
            int c  = px - r * PC;
            int ci = kg * 32 + cl;
            int gi = i0 - 1 + r;
            int gj = j0 - 1 + c;
            float v = 0.f;
            if (gi >= 0 && gi < HH && gj >= 0 && gj < WW) {
                int y0 = gi + s_dy[ci], y1 = y0 + 1;
                int x0 = gj + s_dx[ci], x1 = x0 + 1;
                float fx = s_fx[ci], fy = s_fy[ci];
                const float* xp = xn + ci * (HH * WW);
                float v00 = (y0 >= 0 && y0 < HH && x0 >= 0 && x0 < WW) ? xp[y0 * WW + x0] : 0.f;
                float v01 = (y0 >= 0 && y0 < HH && x1 >= 0 && x1 < WW) ? xp[y0 * WW + x1] : 0.f;
                float v10 = (y1 >= 0 && y1 < HH && x0 >= 0 && x0 < WW) ? xp[y1 * WW + x0] : 0.f;
                float v11 = (y1 >= 0 && y1 < HH && x1 >= 0 && x1 < WW) ? xp[y1 * WW + x1] : 0.f;
                v = (1.f - fy) * ((1.f - fx) * v00 + fx * v01)
                  + fy * ((1.f - fx) * v10 + fx * v11);
            }
            tile[px * CHP + cl] = bf16_rne(v);
        }
        __syncthreads();

        const unsigned short* wk = wbuf + kg * (3 * 9 * 4 * 512);
        #pragma unroll 1
        for (int t = 0; t < 9; ++t) {
            int ky = t / 3, kx = t - ky * 3;
            bf16x8 Af[3][4];
            #pragma unroll
            for (int p = 0; p < 3; ++p)
                #pragma unroll
                for (int mf = 0; mf < 4; ++mf)
                    Af[p][mf] = *(const bf16x8*)(wk + ((size_t)((p * 9 + t) * 4 + mf)) * 512 + l * 8);

            int toff = (ky * PC + kx) * (CHP * 2);
            #pragma unroll
            for (int nf = 0; nf < 8; ++nf) {
                int rl = nf >> 1, cb = nf & 1;
                int off = lds_base + toff + (rl * PC + cb * 16) * (CHP * 2);
                bf16x8 b1 = *(const bf16x8*)(ldsb + off);

                // powers in registers: b2 = bf16(v^2), b3 = bf16(v^2 * v)
                u32x4 bu = __builtin_bit_cast(u32x4, b1);
                unsigned d2[4], d3[4];
                #pragma unroll
                for (int q = 0; q < 4; ++q) {
                    float fl = __builtin_bit_cast(float, bu[q] << 16);
                    float fh = __builtin_bit_cast(float, bu[q] & 0xffff0000u);
                    float fl2 = fl * fl, fh2 = fh * fh;
                    float fl3 = fl2 * fl, fh3 = fh2 * fh;
                    d2[q] = pack_bf16x2(fl2, fh2);
                    d3[q] = pack_bf16x2(fl3, fh3);
                }
                bf16x8 b2 = __builtin_bit_cast(bf16x8, (u32x4){d2[0], d2[1], d2[2], d2[3]});
                bf16x8 b3 = __builtin_bit_cast(bf16x8, (u32x4){d3[0], d3[1], d3[2], d3[3]});

                #pragma unroll
                for (int mf = 0; mf < 4; ++mf)
                    acc[mf][nf] = __builtin_amdgcn_mfma_f32_16x16x32_bf16(Af[0][mf], b1, acc[mf][nf], 0, 0, 0);
                #pragma unroll
                for (int mf = 0; mf < 4; ++mf)
                    acc[mf][nf] = __builtin_amdgcn_mfma_f32_16x16x32_bf16(Af[1][mf], b2, acc[mf][nf], 0, 0, 0);
                #pragma unroll
                for (int mf = 0; mf < 4; ++mf)
                    acc[mf][nf] = __builtin_amdgcn_mfma_f32_16x16x32_bf16(Af[2][mf], b3, acc[mf][nf], 0, 0, 0);
            }
        }
    }

    // ---- epilogue ----
    #pragma unroll
    for (int mf = 0; mf < 4; ++mf) {
        #pragma unroll
        for (int nf = 0; nf < 8; ++nf) {
            int rl = nf >> 1, cb = nf & 1;
            int row = i0 + wv * 4 + rl;
            int col = j0 + cb * 16 + lm;
            #pragma unroll
            for (int r = 0; r < 4; ++r) {
                int co = mf * 16 + lg * 4 + r;
                out[((n * C_OUT + co) * HH + row) * WW + col] = acc[mf][nf][r];
            }
        }
    }
}

// ============ fp32 fallback (round-1 kernel, used only if ws too small) ============
#define TS 32
#define CI_G 16
#define PTS (TS + 2)
#define CO_CHUNK 16
#define W_STRIDE_CO (192 * 9)
#define W_STRIDE_P  (64 * 9)

__global__ __launch_bounds__(256)
void conv_fp32(const float* __restrict__ src,
               const float* __restrict__ shifts,
               const float* __restrict__ weight,
               const float* __restrict__ bias,
               float* __restrict__ out) {
    __shared__ float tile[CI_G][PTS][PTS];
    __shared__ float s_fx[C_IN], s_fy[C_IN];
    __shared__ int s_dx0[C_IN], s_dy0[C_IN];

    int bid = blockIdx.x;
    int tj = bid & 3;
    int ti = (bid >> 2) & 3;
    int n  = bid >> 4;
    int i0 = ti * TS, j0 = tj * TS;

    int tid = threadIdx.x;
    int tx = tid & 31;
    int ty = tid >> 5;

    if (tid < C_IN) {
        float sx = shifts[2 * tid] * MAX_SHIFT;
        float sy = shifts[2 * tid + 1] * MAX_SHIFT;
        float fx0 = floorf(sx), fy0 = floorf(sy);
        s_dx0[tid] = (int)fx0; s_dy0[tid] = (int)fy0;
        s_fx[tid] = sx - fx0;  s_fy[tid] = sy - fy0;
    }
    __syncthreads();

    const float* xn = src + n * (C_IN * HH * WW);

    for (int cc = 0; cc < C_OUT / CO_CHUNK; ++cc) {
        float acc[CO_CHUNK][4];
        #pragma unroll
        for (int co = 0; co < CO_CHUNK; ++co) {
            float b = bias[cc * CO_CHUNK + co];
            #pragma unroll
            for (int k = 0; k < 4; ++k) acc[co][k] = b;
        }
        for (int cg = 0; cg < C_IN / CI_G; ++cg) {
            __syncthreads();
            for (int e = tid; e < CI_G * PTS * PTS; e += 256) {
                int cl  = e / (PTS * PTS);
                int rem = e - cl * (PTS * PTS);
                int y   = rem / PTS;
                int xq  = rem - y * PTS;
                int gi = i0 - 1 + y, gj = j0 - 1 + xq;
                int c = cg * CI_G + cl;
                float v = 0.f;
                if (gi >= 0 && gi < HH && gj >= 0 && gj < WW) {
                    int y0 = gi + s_dy0[c], y1 = y0 + 1;
                    int x0 = gj + s_dx0[c], x1 = x0 + 1;
                    float fx = s_fx[c], fy = s_fy[c];
                    const float* xp = xn + c * HH * WW;
                    float v00 = (y0 >= 0 && y0 < HH && x0 >= 0 && x0 < WW) ? xp[y0 * WW + x0] : 0.f;
                    float v01 = (y0 >= 0 && y0 < HH && x1 >= 0 && x1 < WW) ? xp[y0 * WW + x1] : 0.f;
                    float v10 = (y1 >= 0 && y1 < HH && x0 >= 0 && x0 < WW) ? xp[y1 * WW + x0] : 0.f;
                    float v11 = (y1 >= 0 && y1 < HH && x1 >= 0 && x1 < WW) ? xp[y1 * WW + x1] : 0.f;
                    v = (1.f - fy) * ((1.f - fx) * v00 + fx * v01)
                      + fy * ((1.f - fx) * v10 + fx * v11);
                }
                tile[cl][y][xq] = v;
            }
            __syncthreads();
            #pragma unroll 1
            for (int cl = 0; cl < CI_G; ++cl) {
                int ci = cg * CI_G + cl;
                const float* wp = weight + (cc * CO_CHUNK) * W_STRIDE_CO + ci * 9;
                #pragma unroll
                for (int ky = 0; ky < 3; ++ky) {
                    #pragma unroll
                    for (int kx = 0; kx < 3; ++kx) {
                        int tap = ky * 3 + kx;
                        float v1[4], v2[4], v3[4];
                        #pragma unroll
                        for (int k = 0; k < 4; ++k) {
                            float t = tile[cl][ty + k * 8 + ky][tx + kx];
                            v1[k] = t; v2[k] = t * t; v3[k] = v2[k] * t;
                        }
                        #pragma unroll
                        for (int co = 0; co < CO_CHUNK; ++co) {
                            float w1 = wp[co * W_STRIDE_CO + 0 * W_STRIDE_P + tap];
                            float w2 = wp[co * W_STRIDE_CO + 1 * W_STRIDE_P + tap];
                            float w3 = wp[co * W_STRIDE_CO + 2 * W_STRIDE_P + tap];
                            #pragma unroll
                            for (int k = 0; k < 4; ++k) {
                                acc[co][k] += w1 * v1[k];
                                acc[co][k] += w2 * v2[k];
                                acc[co][k] += w3 * v3[k];
                            }
                        }
                    }
                }
            }
        }
        #pragma unroll
        for (int co = 0; co < CO_CHUNK; ++co) {
            int oc = cc * CO_CHUNK + co;
            #pragma unroll
            for (int k = 0; k < 4; ++k) {
                int i = i0 + ty + k * 8;
                out[((n * C_OUT + oc) * HH + i) * WW + (j0 + tx)] = acc[co][k];
            }
        }
    }
}

extern "C" void kernel_launch(void* const* d_in, const int* in_sizes, int n_in,
                              void* d_out, int out_size, void* d_ws, size_t ws_size,
                              hipStream_t stream) {
    (void)in_sizes; (void)n_in; (void)out_size;
    const float* x      = (const float*)d_in[0];
    const float* weight = (const float*)d_in[1];
    const float* bias   = (const float*)d_in[2];
    const float* shifts = (const float*)d_in[3];
    float* out = (float*)d_out;

    const size_t wbuf_bytes = 110592 * sizeof(unsigned short);  // 216 KiB

    if (ws_size >= wbuf_bytes) {
        unsigned short* wbuf = (unsigned short*)d_ws;
        prep_w<<<432, 256, 0, stream>>>(weight, wbuf);
        conv_mfma<<<512, 256, 0, stream>>>(x, shifts, wbuf, bias, out);
    } else {
        conv_fp32<<<NB * 4 * 4, 256, 0, stream>>>(x, shifts, weight, bias, out);
    }
}

// Round 4
// 132.588 us; speedup vs baseline: 11.7029x; 1.1018x over previous
//
#include <hip/hip_runtime.h>
#include <hip/hip_bf16.h>
#include <math.h>

#define NB 16
#define C_IN 64
#define C_OUT 64
#define HH 128
#define WW 128
#define MAX_SHIFT 4.0f

typedef __attribute__((ext_vector_type(8))) short bf16x8;
typedef __attribute__((ext_vector_type(4))) float f32x4;
typedef __attribute__((ext_vector_type(4))) unsigned int u32x4;

__device__ inline unsigned short bf16_rne(float f) {
    unsigned u = __builtin_bit_cast(unsigned, f);
    u += 0x7fffu + ((u >> 16) & 1u);
    return (unsigned short)(u >> 16);
}
__device__ inline unsigned pack_bf16x2(float lo, float hi) {
    unsigned ul = __builtin_bit_cast(unsigned, lo);
    unsigned uh = __builtin_bit_cast(unsigned, hi);
    ul += 0x7fffu + ((ul >> 16) & 1u);
    uh += 0x7fffu + ((uh >> 16) & 1u);
    return (ul >> 16) | (uh & 0xffff0000u);
}

// =====================================================================
// PASS 1: per-channel bilinear shift + powers -> xsp[n][h][w][k192] bf16
//         k = p*64 + c  (matches weight k-order)
// =====================================================================
__global__ __launch_bounds__(256)
void shift_pow(const float* __restrict__ x, const float* __restrict__ shifts,
               unsigned short* __restrict__ xsp) {
    __shared__ unsigned short row[128 * 208];   // [w][208 u16], 53,248 B

    int b = blockIdx.x;
    int h = b & 127;
    int n = b >> 7;
    int tid = threadIdx.x;
    int c = tid >> 2;      // 0..63
    int q = tid & 3;       // w = q + 4j

    float sx = shifts[2 * c] * MAX_SHIFT;
    float sy = shifts[2 * c + 1] * MAX_SHIFT;
    float fx0 = floorf(sx), fy0 = floorf(sy);
    int dx = (int)fx0, dy = (int)fy0;
    float fx = sx - fx0, fy = sy - fy0;

    const float* xp = x + (size_t)(n * C_IN + c) * (HH * WW);
    int y0 = h + dy, y1 = y0 + 1;
    bool vy0 = (y0 >= 0 && y0 < HH), vy1 = (y1 >= 0 && y1 < HH);
    const float* r0 = xp + y0 * WW;
    const float* r1 = xp + y1 * WW;

    #pragma unroll 4
    for (int j = 0; j < 32; ++j) {
        int w = q + j * 4;
        int x0 = w + dx, x1 = x0 + 1;
        bool vx0 = (x0 >= 0 && x0 < WW), vx1 = (x1 >= 0 && x1 < WW);
        float v00 = (vy0 && vx0) ? r0[x0] : 0.f;
        float v01 = (vy0 && vx1) ? r0[x1] : 0.f;
        float v10 = (vy1 && vx0) ? r1[x0] : 0.f;
        float v11 = (vy1 && vx1) ? r1[x1] : 0.f;
        float v = (1.f - fy) * ((1.f - fx) * v00 + fx * v01)
                + fy * ((1.f - fx) * v10 + fx * v11);
        float v2 = v * v, v3 = v2 * v;
        unsigned short* rw = row + w * 208;
        rw[c]       = bf16_rne(v);
        rw[64 + c]  = bf16_rne(v2);
        rw[128 + c] = bf16_rne(v3);
    }
    __syncthreads();

    // coalesced writeout: [w][192] contiguous = 49152 B per (n,h)
    char* dst = (char*)(xsp + (size_t)(n * HH + h) * (WW * 192));
    const char* rb = (const char*)row;
    #pragma unroll
    for (int it = 0; it < 12; ++it) {
        int o = it * 4096 + tid * 16;
        int w = o / 384;
        int ko = o - w * 384;
        u32x4 d = *(const u32x4*)(rb + w * 416 + ko);
        *(u32x4*)(dst + o) = d;
    }
}

// =====================================================================
// weight prep for pass 2: [t9][kb6][mf4][lane64][e8] bf16
// =====================================================================
__global__ void prep_w2(const float* __restrict__ w, unsigned short* __restrict__ wbuf) {
    int id = blockIdx.x * 256 + threadIdx.x;   // < 110592
    int e = id & 7;
    int l = (id >> 3) & 63;
    int f = id >> 9;          // 0..215
    int mf = f & 3;
    int f2 = f >> 2;          // 0..53
    int kb = f2 % 6;
    int t  = f2 / 6;
    int k  = kb * 32 + (l >> 4) * 8 + e;   // 0..191
    int p  = k >> 6;
    int c  = k & 63;
    int co = mf * 16 + (l & 15);
    wbuf[id] = bf16_rne(w[(co * 192 + p * 64 + c) * 9 + t]);
}

// =====================================================================
// PASS 2: implicit-GEMM conv, pure copy staging
// =====================================================================
__global__ __launch_bounds__(256, 2)
void conv2(const unsigned short* __restrict__ xsp,
           const unsigned short* __restrict__ wbuf,
           const float* __restrict__ bias,
           float* __restrict__ out) {
    __shared__ unsigned short tile[612 * 40];   // [px 18x34][32k + 8 pad], 48,960 B

    int bid = blockIdx.x;
    int wg = (bid & 7) * 64 + (bid >> 3);       // bijective XCD swizzle (512 = 8*64)
    int n  = wg >> 5;
    int t5 = wg & 31;
    int i0 = (t5 >> 2) * 16;
    int j0 = (t5 & 3) * 32;

    int tid = threadIdx.x;
    int l  = tid & 63;
    int wv = tid >> 6;
    int lm = l & 15;
    int lg = l >> 4;

    f32x4 acc[4][8];
    #pragma unroll
    for (int mf = 0; mf < 4; ++mf) {
        #pragma unroll
        for (int r = 0; r < 4; ++r) {
            float bv = bias[mf * 16 + lg * 4 + r];
            #pragma unroll
            for (int nf = 0; nf < 8; ++nf) acc[mf][nf][r] = bv;
        }
    }

    const unsigned short* xn = xsp + (size_t)n * (HH * WW * 192);
    int lds_base = ((wv * 4) * 34 + lm) * 80 + lg * 16;   // bytes

    #pragma unroll 1
    for (int kb = 0; kb < 6; ++kb) {
        __syncthreads();
        // ---- stage: 612 px x 64 B (k-block) ----
        #pragma unroll
        for (int it = 0; it < 10; ++it) {
            int ch = it * 256 + tid;          // chunk id, need 2448
            if (ch < 2448) {
                int px = ch >> 2, sub = ch & 3;
                int r  = px / 34;
                int cc = px - r * 34;
                int gi = i0 - 1 + r, gj = j0 - 1 + cc;
                u32x4 d = {0, 0, 0, 0};
                if (gi >= 0 && gi < HH && gj >= 0 && gj < WW)
                    d = *(const u32x4*)(xn + ((gi * WW + gj) * 192 + kb * 32 + sub * 8));
                *(u32x4*)((char*)tile + px * 80 + sub * 16) = d;
            }
        }
        __syncthreads();

        // ---- compute: 9 taps x 8 nf x 4 mf MFMAs ----
        bf16x8 Af[4];
        #pragma unroll
        for (int mf = 0; mf < 4; ++mf)
            Af[mf] = *(const bf16x8*)(wbuf + (size_t)((0 * 6 + kb) * 4 + mf) * 512 + l * 8);

        #pragma unroll 1
        for (int t = 0; t < 9; ++t) {
            bf16x8 Afn[4];
            int tn = (t < 8) ? t + 1 : t;
            #pragma unroll
            for (int mf = 0; mf < 4; ++mf)
                Afn[mf] = *(const bf16x8*)(wbuf + (size_t)((tn * 6 + kb) * 4 + mf) * 512 + l * 8);

            int ky = t / 3, kx = t - ky * 3;
            int toff = (ky * 34 + kx) * 80;
            #pragma unroll
            for (int nf = 0; nf < 8; ++nf) {
                int rl = nf >> 1, cb = nf & 1;
                int off = lds_base + toff + (rl * 34 + cb * 16) * 80;
                bf16x8 bfrag = *(const bf16x8*)((const char*)tile + off);
                #pragma unroll
                for (int mf = 0; mf < 4; ++mf)
                    acc[mf][nf] = __builtin_amdgcn_mfma_f32_16x16x32_bf16(Af[mf], bfrag, acc[mf][nf], 0, 0, 0);
            }
            #pragma unroll
            for (int mf = 0; mf < 4; ++mf) Af[mf] = Afn[mf];
        }
    }

    // ---- epilogue ----
    #pragma unroll
    for (int mf = 0; mf < 4; ++mf) {
        #pragma unroll
        for (int nf = 0; nf < 8; ++nf) {
            int rl = nf >> 1, cb = nf & 1;
            int row = i0 + wv * 4 + rl;
            int col = j0 + cb * 16 + lm;
            #pragma unroll
            for (int r = 0; r < 4; ++r) {
                int co = mf * 16 + lg * 4 + r;
                out[((n * C_OUT + co) * HH + row) * WW + col] = acc[mf][nf][r];
            }
        }
    }
}

// =====================================================================
// Fallback tier 2: round-3 fused kernel (ws >= 216 KB only)
// =====================================================================
#define TH 16
#define TW 32
#define PR (TH + 2)
#define PC (TW + 2)
#define NPX (PR * PC)
#define CHP 40

__global__ void prep_w_fused(const float* __restrict__ w, unsigned short* __restrict__ wbuf) {
    int id = blockIdx.x * 256 + threadIdx.x;
    int e = id & 7;
    int l = (id >> 3) & 63;
    int frag = id >> 9;
    int mf = frag & 3;
    int f2 = frag >> 2;
    int t = f2 % 9;
    int f3 = f2 / 9;
    int p = f3 % 3;
    int kg = f3 / 3;
    int co = mf * 16 + (l & 15);
    int ci = kg * 32 + (l >> 4) * 8 + e;
    wbuf[id] = bf16_rne(w[(co * 192 + p * 64 + ci) * 9 + t]);
}

__global__ __launch_bounds__(256, 2)
void conv_fused(const float* __restrict__ x,
                const float* __restrict__ shifts,
                const unsigned short* __restrict__ wbuf,
                const float* __restrict__ bias,
                float* __restrict__ out) {
    __shared__ unsigned short tile[NPX * CHP];
    __shared__ float s_fx[C_IN], s_fy[C_IN];
    __shared__ int s_dx[C_IN], s_dy[C_IN];

    int bid = blockIdx.x;
    int wg = (bid & 7) * 64 + (bid >> 3);
    int n  = wg >> 5;
    int t5 = wg & 31;
    int i0 = (t5 >> 2) * TH;
    int j0 = (t5 & 3) * TW;

    int tid = threadIdx.x;
    int l  = tid & 63;
    int wv = tid >> 6;
    int lm = l & 15;
    int lg = l >> 4;

    if (tid < C_IN) {
        float sx = shifts[2 * tid] * MAX_SHIFT;
        float sy = shifts[2 * tid + 1] * MAX_SHIFT;
        float fx0 = floorf(sx), fy0 = floorf(sy);
        s_dx[tid] = (int)fx0; s_dy[tid] = (int)fy0;
        s_fx[tid] = sx - fx0;  s_fy[tid] = sy - fy0;
    }

    f32x4 acc[4][8];
    #pragma unroll
    for (int mf = 0; mf < 4; ++mf) {
        #pragma unroll
        for (int r = 0; r < 4; ++r) {
            float b = bias[mf * 16 + lg * 4 + r];
            #pragma unroll
            for (int nf = 0; nf < 8; ++nf) acc[mf][nf][r] = b;
        }
    }

    const float* xn = x + n * (C_IN * HH * WW);
    const char* ldsb = (const char*)tile;
    int lds_base = ((wv * 4) * PC + lm) * (CHP * 2) + lg * 16;

    #pragma unroll 1
    for (int kg = 0; kg < 2; ++kg) {
        __syncthreads();
        for (int e = tid; e < NPX * 32; e += 256) {
            int cl = e / NPX;
            int px = e - cl * NPX;
            int r  = px / PC;
            int c  = px - r * PC;
            int ci = kg * 32 + cl;
            int gi = i0 - 1 + r;
            int gj = j0 - 1 + c;
            float v = 0.f;
            if (gi >= 0 && gi < HH && gj >= 0 && gj < WW) {
                int y0 = gi + s_dy[ci], y1 = y0 + 1;
                int x0 = gj + s_dx[ci], x1 = x0 + 1;
                float fx = s_fx[ci], fy = s_fy[ci];
                const float* xp = xn + ci * (HH * WW);
                float v00 = (y0 >= 0 && y0 < HH && x0 >= 0 && x0 < WW) ? xp[y0 * WW + x0] : 0.f;
                float v01 = (y0 >= 0 && y0 < HH && x1 >= 0 && x1 < WW) ? xp[y0 * WW + x1] : 0.f;
                float v10 = (y1 >= 0 && y1 < HH && x0 >= 0 && x0 < WW) ? xp[y1 * WW + x0] : 0.f;
                float v11 = (y1 >= 0 && y1 < HH && x1 >= 0 && x1 < WW) ? xp[y1 * WW + x1] : 0.f;
                v = (1.f - fy) * ((1.f - fx) * v00 + fx * v01)
                  + fy * ((1.f - fx) * v10 + fx * v11);
            }
            tile[px * CHP + cl] = bf16_rne(v);
        }
        __syncthreads();

        const unsigned short* wk = wbuf + kg * (3 * 9 * 4 * 512);
        #pragma unroll 1
        for (int t = 0; t < 9; ++t) {
            int ky = t / 3, kx = t - ky * 3;
            bf16x8 Af[3][4];
            #pragma unroll
            for (int p = 0; p < 3; ++p)
                #pragma unroll
                for (int mf = 0; mf < 4; ++mf)
                    Af[p][mf] = *(const bf16x8*)(wk + ((size_t)((p * 9 + t) * 4 + mf)) * 512 + l * 8);

            int toff = (ky * PC + kx) * (CHP * 2);
            #pragma unroll
            for (int nf = 0; nf < 8; ++nf) {
                int rl = nf >> 1, cb = nf & 1;
                int off = lds_base + toff + (rl * PC + cb * 16) * (CHP * 2);
                bf16x8 b1 = *(const bf16x8*)(ldsb + off);
                u32x4 bu = __builtin_bit_cast(u32x4, b1);
                unsigned d2[4], d3[4];
                #pragma unroll
                for (int q = 0; q < 4; ++q) {
                    float fl = __builtin_bit_cast(float, bu[q] << 16);
                    float fh = __builtin_bit_cast(float, bu[q] & 0xffff0000u);
                    float fl2 = fl * fl, fh2 = fh * fh;
                    float fl3 = fl2 * fl, fh3 = fh2 * fh;
                    d2[q] = pack_bf16x2(fl2, fh2);
                    d3[q] = pack_bf16x2(fl3, fh3);
                }
                bf16x8 b2 = __builtin_bit_cast(bf16x8, (u32x4){d2[0], d2[1], d2[2], d2[3]});
                bf16x8 b3 = __builtin_bit_cast(bf16x8, (u32x4){d3[0], d3[1], d3[2], d3[3]});
                #pragma unroll
                for (int mf = 0; mf < 4; ++mf)
                    acc[mf][nf] = __builtin_amdgcn_mfma_f32_16x16x32_bf16(Af[0][mf], b1, acc[mf][nf], 0, 0, 0);
                #pragma unroll
                for (int mf = 0; mf < 4; ++mf)
                    acc[mf][nf] = __builtin_amdgcn_mfma_f32_16x16x32_bf16(Af[1][mf], b2, acc[mf][nf], 0, 0, 0);
                #pragma unroll
                for (int mf = 0; mf < 4; ++mf)
                    acc[mf][nf] = __builtin_amdgcn_mfma_f32_16x16x32_bf16(Af[2][mf], b3, acc[mf][nf], 0, 0, 0);
            }
        }
    }

    #pragma unroll
    for (int mf = 0; mf < 4; ++mf) {
        #pragma unroll
        for (int nf = 0; nf < 8; ++nf) {
            int rl = nf >> 1, cb = nf & 1;
            int row = i0 + wv * 4 + rl;
            int col = j0 + cb * 16 + lm;
            #pragma unroll
            for (int r = 0; r < 4; ++r) {
                int co = mf * 16 + lg * 4 + r;
                out[((n * C_OUT + co) * HH + row) * WW + col] = acc[mf][nf][r];
            }
        }
    }
}

extern "C" void kernel_launch(void* const* d_in, const int* in_sizes, int n_in,
                              void* d_out, int out_size, void* d_ws, size_t ws_size,
                              hipStream_t stream) {
    (void)in_sizes; (void)n_in; (void)out_size;
    const float* x      = (const float*)d_in[0];
    const float* weight = (const float*)d_in[1];
    const float* bias   = (const float*)d_in[2];
    const float* shifts = (const float*)d_in[3];
    float* out = (float*)d_out;

    const size_t xsp_elems = (size_t)NB * HH * WW * 192;        // u16 count
    const size_t need2 = xsp_elems * 2 + 110592 * 2;            // ~100.9 MB
    const size_t need1 = 110592 * 2;                            // 216 KB

    if (ws_size >= need2) {
        unsigned short* xsp  = (unsigned short*)d_ws;
        unsigned short* wbuf = xsp + xsp_elems;
        prep_w2<<<432, 256, 0, stream>>>(weight, wbuf);
        shift_pow<<<NB * HH, 256, 0, stream>>>(x, shifts, xsp);
        conv2<<<512, 256, 0, stream>>>(xsp, wbuf, bias, out);
    } else if (ws_size >= need1) {
        unsigned short* wbuf = (unsigned short*)d_ws;
        prep_w_fused<<<432, 256, 0, stream>>>(weight, wbuf);
        conv_fused<<<512, 256, 0, stream>>>(x, shifts, wbuf, bias, out);
    } else {
        // no-ws fallback: fused kernel needs wbuf; assume harness provides ws.
        // As a last resort, still run fused path using out as temp is unsafe;
        // simply launch fused with a null-weight guard is wrong — so require ws.
        // (Harness always provides >= need1 in practice; tier-3 removed.)
        unsigned short* wbuf = (unsigned short*)d_ws;
        prep_w_fused<<<432, 256, 0, stream>>>(weight, wbuf);
        conv_fused<<<512, 256, 0, stream>>>(x, shifts, wbuf, bias, out);
    }
}

// Round 5
// 130.315 us; speedup vs baseline: 11.9071x; 1.0174x over previous
//
#include <hip/hip_runtime.h>
#include <hip/hip_bf16.h>
#include <math.h>

#define NB 16
#define C_IN 64
#define C_OUT 64
#define HH 128
#define WW 128
#define MAX_SHIFT 4.0f

typedef __attribute__((ext_vector_type(8))) short bf16x8;
typedef __attribute__((ext_vector_type(4))) float f32x4;
typedef __attribute__((ext_vector_type(4))) unsigned int u32x4;

__device__ inline unsigned short bf16_rne(float f) {
    unsigned u = __builtin_bit_cast(unsigned, f);
    u += 0x7fffu + ((u >> 16) & 1u);
    return (unsigned short)(u >> 16);
}
__device__ inline unsigned pack_bf16x2(float lo, float hi) {
    unsigned ul = __builtin_bit_cast(unsigned, lo);
    unsigned uh = __builtin_bit_cast(unsigned, hi);
    ul += 0x7fffu + ((ul >> 16) & 1u);
    uh += 0x7fffu + ((uh >> 16) & 1u);
    return (ul >> 16) | (uh & 0xffff0000u);
}

// =====================================================================
// PASS 1 v2: coalesced bilinear shift + powers -> xsp[n][h][w][k192] bf16
//   k = p*64 + c (matches weight k-order)
//   wave-lane <-> consecutive w of ONE channel => 256B coalesced reads
//   LDS row stride 202 u16 (dword stride 101, odd) => conflict-free writes
// =====================================================================
#define RSTR 202   // u16 stride per w in LDS transpose buffer

__global__ __launch_bounds__(256)
void shift_pow(const float* __restrict__ x, const float* __restrict__ shifts,
               unsigned short* __restrict__ xsp) {
    __shared__ unsigned short row[128 * RSTR];   // 51,712 B
    __shared__ float s_fx[C_IN], s_fy[C_IN];
    __shared__ int s_dx[C_IN], s_dy[C_IN];

    int b = blockIdx.x;
    int h = b & 127;
    int n = b >> 7;
    int tid = threadIdx.x;
    int wv = tid >> 6;
    int l  = tid & 63;

    if (tid < C_IN) {
        float sx = shifts[2 * tid] * MAX_SHIFT;
        float sy = shifts[2 * tid + 1] * MAX_SHIFT;
        float fx0 = floorf(sx), fy0 = floorf(sy);
        s_dx[tid] = (int)fx0; s_dy[tid] = (int)fy0;
        s_fx[tid] = sx - fx0;  s_fy[tid] = sy - fy0;
    }
    __syncthreads();

    const float* xn = x + (size_t)n * (C_IN * HH * WW);

    #pragma unroll 2
    for (int it = 0; it < 16; ++it) {
        int c = it * 4 + wv;
        int dx = s_dx[c], dy = s_dy[c];
        float fx = s_fx[c], fy = s_fy[c];
        const float* xp = xn + (size_t)c * (HH * WW);
        int y0 = h + dy, y1 = y0 + 1;
        bool vy0 = ((unsigned)y0 < (unsigned)HH);
        bool vy1 = ((unsigned)y1 < (unsigned)HH);
        const float* r0 = xp + y0 * WW;
        const float* r1 = xp + y1 * WW;

        #pragma unroll
        for (int hf = 0; hf < 2; ++hf) {
            int w = hf * 64 + l;
            int x0 = w + dx, x1 = x0 + 1;
            bool vx0 = ((unsigned)x0 < (unsigned)WW);
            bool vx1 = ((unsigned)x1 < (unsigned)WW);
            float v00 = (vy0 && vx0) ? r0[x0] : 0.f;
            float v01 = (vy0 && vx1) ? r0[x1] : 0.f;
            float v10 = (vy1 && vx0) ? r1[x0] : 0.f;
            float v11 = (vy1 && vx1) ? r1[x1] : 0.f;
            float v = (1.f - fy) * ((1.f - fx) * v00 + fx * v01)
                    + fy * ((1.f - fx) * v10 + fx * v11);
            float v2 = v * v, v3 = v2 * v;
            unsigned short* rw = row + w * RSTR;
            rw[c]       = bf16_rne(v);
            rw[64 + c]  = bf16_rne(v2);
            rw[128 + c] = bf16_rne(v3);
        }
    }
    __syncthreads();

    // writeout: [w][192] contiguous, 12288 u32 per (n,h); scalar-u32 lanes
    unsigned* dst = (unsigned*)(xsp + (size_t)(n * HH + h) * (WW * 192));
    const unsigned* rp = (const unsigned*)row;
    #pragma unroll
    for (int itw = 0; itw < 48; ++itw) {
        int o32 = itw * 256 + tid;
        int w = o32 / 96;                 // 96 u32 of payload per w
        int k4 = o32 - w * 96;
        dst[o32] = rp[w * (RSTR / 2) + k4];
    }
}

// =====================================================================
// weight prep for pass 2: [t9][kb6][mf4][lane64][e8] bf16
// =====================================================================
__global__ void prep_w2(const float* __restrict__ w, unsigned short* __restrict__ wbuf) {
    int id = blockIdx.x * 256 + threadIdx.x;   // < 110592
    int e = id & 7;
    int l = (id >> 3) & 63;
    int f = id >> 9;          // 0..215
    int mf = f & 3;
    int f2 = f >> 2;          // 0..53
    int kb = f2 % 6;
    int t  = f2 / 6;
    int k  = kb * 32 + (l >> 4) * 8 + e;   // 0..191
    int p  = k >> 6;
    int c  = k & 63;
    int co = mf * 16 + (l & 15);
    wbuf[id] = bf16_rne(w[(co * 192 + p * 64 + c) * 9 + t]);
}

// =====================================================================
// PASS 2: implicit-GEMM conv, pure copy staging (unchanged from round 4)
// =====================================================================
__global__ __launch_bounds__(256, 2)
void conv2(const unsigned short* __restrict__ xsp,
           const unsigned short* __restrict__ wbuf,
           const float* __restrict__ bias,
           float* __restrict__ out) {
    __shared__ unsigned short tile[612 * 40];   // [px 18x34][32k + 8 pad], 48,960 B

    int bid = blockIdx.x;
    int wg = (bid & 7) * 64 + (bid >> 3);       // bijective XCD swizzle (512 = 8*64)
    int n  = wg >> 5;
    int t5 = wg & 31;
    int i0 = (t5 >> 2) * 16;
    int j0 = (t5 & 3) * 32;

    int tid = threadIdx.x;
    int l  = tid & 63;
    int wv = tid >> 6;
    int lm = l & 15;
    int lg = l >> 4;

    f32x4 acc[4][8];
    #pragma unroll
    for (int mf = 0; mf < 4; ++mf) {
        #pragma unroll
        for (int r = 0; r < 4; ++r) {
            float bv = bias[mf * 16 + lg * 4 + r];
            #pragma unroll
            for (int nf = 0; nf < 8; ++nf) acc[mf][nf][r] = bv;
        }
    }

    const unsigned short* xn = xsp + (size_t)n * (HH * WW * 192);
    int lds_base = ((wv * 4) * 34 + lm) * 80 + lg * 16;   // bytes

    #pragma unroll 1
    for (int kb = 0; kb < 6; ++kb) {
        __syncthreads();
        // ---- stage: 612 px x 64 B (k-block) ----
        #pragma unroll
        for (int it = 0; it < 10; ++it) {
            int ch = it * 256 + tid;          // chunk id, need 2448
            if (ch < 2448) {
                int px = ch >> 2, sub = ch & 3;
                int r  = px / 34;
                int cc = px - r * 34;
                int gi = i0 - 1 + r, gj = j0 - 1 + cc;
                u32x4 d = {0, 0, 0, 0};
                if (gi >= 0 && gi < HH && gj >= 0 && gj < WW)
                    d = *(const u32x4*)(xn + ((gi * WW + gj) * 192 + kb * 32 + sub * 8));
                *(u32x4*)((char*)tile + px * 80 + sub * 16) = d;
            }
        }
        __syncthreads();

        // ---- compute: 9 taps x 8 nf x 4 mf MFMAs ----
        bf16x8 Af[4];
        #pragma unroll
        for (int mf = 0; mf < 4; ++mf)
            Af[mf] = *(const bf16x8*)(wbuf + (size_t)((0 * 6 + kb) * 4 + mf) * 512 + l * 8);

        #pragma unroll 1
        for (int t = 0; t < 9; ++t) {
            bf16x8 Afn[4];
            int tn = (t < 8) ? t + 1 : t;
            #pragma unroll
            for (int mf = 0; mf < 4; ++mf)
                Afn[mf] = *(const bf16x8*)(wbuf + (size_t)((tn * 6 + kb) * 4 + mf) * 512 + l * 8);

            int ky = t / 3, kx = t - ky * 3;
            int toff = (ky * 34 + kx) * 80;
            #pragma unroll
            for (int nf = 0; nf < 8; ++nf) {
                int rl = nf >> 1, cb = nf & 1;
                int off = lds_base + toff + (rl * 34 + cb * 16) * 80;
                bf16x8 bfrag = *(const bf16x8*)((const char*)tile + off);
                #pragma unroll
                for (int mf = 0; mf < 4; ++mf)
                    acc[mf][nf] = __builtin_amdgcn_mfma_f32_16x16x32_bf16(Af[mf], bfrag, acc[mf][nf], 0, 0, 0);
            }
            #pragma unroll
            for (int mf = 0; mf < 4; ++mf) Af[mf] = Afn[mf];
        }
    }

    // ---- epilogue ----
    #pragma unroll
    for (int mf = 0; mf < 4; ++mf) {
        #pragma unroll
        for (int nf = 0; nf < 8; ++nf) {
            int rl = nf >> 1, cb = nf & 1;
            int row = i0 + wv * 4 + rl;
            int col = j0 + cb * 16 + lm;
            #pragma unroll
            for (int r = 0; r < 4; ++r) {
                int co = mf * 16 + lg * 4 + r;
                out[((n * C_OUT + co) * HH + row) * WW + col] = acc[mf][nf][r];
            }
        }
    }
}

// =====================================================================
// Fallback tier: fused kernel (only if ws too small for xsp)
// =====================================================================
#define TH 16
#define TW 32
#define PR (TH + 2)
#define PC (TW + 2)
#define NPX (PR * PC)
#define CHP 40

__global__ void prep_w_fused(const float* __restrict__ w, unsigned short* __restrict__ wbuf) {
    int id = blockIdx.x * 256 + threadIdx.x;
    int e = id & 7;
    int l = (id >> 3) & 63;
    int frag = id >> 9;
    int mf = frag & 3;
    int f2 = frag >> 2;
    int t = f2 % 9;
    int f3 = f2 / 9;
    int p = f3 % 3;
    int kg = f3 / 3;
    int co = mf * 16 + (l & 15);
    int ci = kg * 32 + (l >> 4) * 8 + e;
    wbuf[id] = bf16_rne(w[(co * 192 + p * 64 + ci) * 9 + t]);
}

__global__ __launch_bounds__(256, 2)
void conv_fused(const float* __restrict__ x,
                const float* __restrict__ shifts,
                const unsigned short* __restrict__ wbuf,
                const float* __restrict__ bias,
                float* __restrict__ out) {
    __shared__ unsigned short tile[NPX * CHP];
    __shared__ float s_fx[C_IN], s_fy[C_IN];
    __shared__ int s_dx[C_IN], s_dy[C_IN];

    int bid = blockIdx.x;
    int wg = (bid & 7) * 64 + (bid >> 3);
    int n  = wg >> 5;
    int t5 = wg & 31;
    int i0 = (t5 >> 2) * TH;
    int j0 = (t5 & 3) * TW;

    int tid = threadIdx.x;
    int l  = tid & 63;
    int wv = tid >> 6;
    int lm = l & 15;
    int lg = l >> 4;

    if (tid < C_IN) {
        float sx = shifts[2 * tid] * MAX_SHIFT;
        float sy = shifts[2 * tid + 1] * MAX_SHIFT;
        float fx0 = floorf(sx), fy0 = floorf(sy);
        s_dx[tid] = (int)fx0; s_dy[tid] = (int)fy0;
        s_fx[tid] = sx - fx0;  s_fy[tid] = sy - fy0;
    }

    f32x4 acc[4][8];
    #pragma unroll
    for (int mf = 0; mf < 4; ++mf) {
        #pragma unroll
        for (int r = 0; r < 4; ++r) {
            float b = bias[mf * 16 + lg * 4 + r];
            #pragma unroll
            for (int nf = 0; nf < 8; ++nf) acc[mf][nf][r] = b;
        }
    }

    const float* xn = x + n * (C_IN * HH * WW);
    const char* ldsb = (const char*)tile;
    int lds_base = ((wv * 4) * PC + lm) * (CHP * 2) + lg * 16;

    #pragma unroll 1
    for (int kg = 0; kg < 2; ++kg) {
        __syncthreads();
        for (int e = tid; e < NPX * 32; e += 256) {
            int cl = e / NPX;
            int px = e - cl * NPX;
            int r  = px / PC;
            int c  = px - r * PC;
            int ci = kg * 32 + cl;
            int gi = i0 - 1 + r;
            int gj = j0 - 1 + c;
            float v = 0.f;
            if (gi >= 0 && gi < HH && gj >= 0 && gj < WW) {
                int y0 = gi + s_dy[ci], y1 = y0 + 1;
                int x0 = gj + s_dx[ci], x1 = x0 + 1;
                float fx = s_fx[ci], fy = s_fy[ci];
                const float* xp = xn + ci * (HH * WW);
                float v00 = (y0 >= 0 && y0 < HH && x0 >= 0 && x0 < WW) ? xp[y0 * WW + x0] : 0.f;
                float v01 = (y0 >= 0 && y0 < HH && x1 >= 0 && x1 < WW) ? xp[y0 * WW + x1] : 0.f;
                float v10 = (y1 >= 0 && y1 < HH && x0 >= 0 && x0 < WW) ? xp[y1 * WW + x0] : 0.f;
                float v11 = (y1 >= 0 && y1 < HH && x1 >= 0 && x1 < WW) ? xp[y1 * WW + x1] : 0.f;
                v = (1.f - fy) * ((1.f - fx) * v00 + fx * v01)
                  + fy * ((1.f - fx) * v10 + fx * v11);
            }
            tile[px * CHP + cl] = bf16_rne(v);
        }
        __syncthreads();

        const unsigned short* wk = wbuf + kg * (3 * 9 * 4 * 512);
        #pragma unroll 1
        for (int t = 0; t < 9; ++t) {
            int ky = t / 3, kx = t - ky * 3;
            bf16x8 Af[3][4];
            #pragma unroll
            for (int p = 0; p < 3; ++p)
                #pragma unroll
                for (int mf = 0; mf < 4; ++mf)
                    Af[p][mf] = *(const bf16x8*)(wk + ((size_t)((p * 9 + t) * 4 + mf)) * 512 + l * 8);

            int toff = (ky * PC + kx) * (CHP * 2);
            #pragma unroll
            for (int nf = 0; nf < 8; ++nf) {
                int rl = nf >> 1, cb = nf & 1;
                int off = lds_base + toff + (rl * PC + cb * 16) * (CHP * 2);
                bf16x8 b1 = *(const bf16x8*)(ldsb + off);
                u32x4 bu = __builtin_bit_cast(u32x4, b1);
                unsigned d2[4], d3[4];
                #pragma unroll
                for (int q = 0; q < 4; ++q) {
                    float fl = __builtin_bit_cast(float, bu[q] << 16);
                    float fh = __builtin_bit_cast(float, bu[q] & 0xffff0000u);
                    float fl2 = fl * fl, fh2 = fh * fh;
                    float fl3 = fl2 * fl, fh3 = fh2 * fh;
                    d2[q] = pack_bf16x2(fl2, fh2);
                    d3[q] = pack_bf16x2(fl3, fh3);
                }
                bf16x8 b2 = __builtin_bit_cast(bf16x8, (u32x4){d2[0], d2[1], d2[2], d2[3]});
                bf16x8 b3 = __builtin_bit_cast(bf16x8, (u32x4){d3[0], d3[1], d3[2], d3[3]});
                #pragma unroll
                for (int mf = 0; mf < 4; ++mf)
                    acc[mf][nf] = __builtin_amdgcn_mfma_f32_16x16x32_bf16(Af[0][mf], b1, acc[mf][nf], 0, 0, 0);
                #pragma unroll
                for (int mf = 0; mf < 4; ++mf)
                    acc[mf][nf] = __builtin_amdgcn_mfma_f32_16x16x32_bf16(Af[1][mf], b2, acc[mf][nf], 0, 0, 0);
                #pragma unroll
                for (int mf = 0; mf < 4; ++mf)
                    acc[mf][nf] = __builtin_amdgcn_mfma_f32_16x16x32_bf16(Af[2][mf], b3, acc[mf][nf], 0, 0, 0);
            }
        }
    }

    #pragma unroll
    for (int mf = 0; mf < 4; ++mf) {
        #pragma unroll
        for (int nf = 0; nf < 8; ++nf) {
            int rl = nf >> 1, cb = nf & 1;
            int row = i0 + wv * 4 + rl;
            int col = j0 + cb * 16 + lm;
            #pragma unroll
            for (int r = 0; r < 4; ++r) {
                int co = mf * 16 + lg * 4 + r;
                out[((n * C_OUT + co) * HH + row) * WW + col] = acc[mf][nf][r];
            }
        }
    }
}

extern "C" void kernel_launch(void* const* d_in, const int* in_sizes, int n_in,
                              void* d_out, int out_size, void* d_ws, size_t ws_size,
                              hipStream_t stream) {
    (void)in_sizes; (void)n_in; (void)out_size;
    const float* x      = (const float*)d_in[0];
    const float* weight = (const float*)d_in[1];
    const float* bias   = (const float*)d_in[2];
    const float* shifts = (const float*)d_in[3];
    float* out = (float*)d_out;

    const size_t xsp_elems = (size_t)NB * HH * WW * 192;        // u16 count
    const size_t need2 = xsp_elems * 2 + 110592 * 2;            // ~100.9 MB
    const size_t need1 = 110592 * 2;                            // 216 KB

    if (ws_size >= need2) {
        unsigned short* xsp  = (unsigned short*)d_ws;
        unsigned short* wbuf = xsp + xsp_elems;
        prep_w2<<<432, 256, 0, stream>>>(weight, wbuf);
        shift_pow<<<NB * HH, 256, 0, stream>>>(x, shifts, xsp);
        conv2<<<512, 256, 0, stream>>>(xsp, wbuf, bias, out);
    } else {
        unsigned short* wbuf = (unsigned short*)d_ws;
        prep_w_fused<<<432, 256, 0, stream>>>(weight, wbuf);
        conv_fused<<<512, 256, 0, stream>>>(x, shifts, wbuf, bias, out);
    }
}

// Round 6
// 114.236 us; speedup vs baseline: 13.5830x; 1.1408x over previous
//
#include <hip/hip_runtime.h>
#include <hip/hip_bf16.h>
#include <math.h>

#define NB 16
#define C_IN 64
#define C_OUT 64
#define HH 128
#define WW 128
#define MAX_SHIFT 4.0f

typedef __attribute__((ext_vector_type(8))) short bf16x8;
typedef __attribute__((ext_vector_type(4))) float f32x4;
typedef __attribute__((ext_vector_type(4))) unsigned int u32x4;

__device__ inline unsigned short bf16_rne(float f) {
    unsigned u = __builtin_bit_cast(unsigned, f);
    u += 0x7fffu + ((u >> 16) & 1u);
    return (unsigned short)(u >> 16);
}
__device__ inline unsigned pack_bf16x2(float lo, float hi) {
    unsigned ul = __builtin_bit_cast(unsigned, lo);
    unsigned uh = __builtin_bit_cast(unsigned, hi);
    ul += 0x7fffu + ((ul >> 16) & 1u);
    uh += 0x7fffu + ((uh >> 16) & 1u);
    return (ul >> 16) | (uh & 0xffff0000u);
}

// =====================================================================
// PASS 1 v3: half-row blocks for occupancy/latency
//   block = (n, h, w-half of 64) ; grid 4096 ; LDS 25.9 KB -> 6 blocks/CU
//   xsp[n][h][w][k192], k = p*64 + c (matches weight k-order)
// =====================================================================
#define RSTR 202   // u16 stride per w in LDS (odd dword stride 101 -> conflict-free)

__global__ __launch_bounds__(256)
void shift_pow(const float* __restrict__ x, const float* __restrict__ shifts,
               unsigned short* __restrict__ xsp) {
    __shared__ unsigned short row[64 * RSTR];   // 25,856 B
    __shared__ float s_fx[C_IN], s_fy[C_IN];
    __shared__ int s_dx[C_IN], s_dy[C_IN];

    int b = blockIdx.x;            // [n16][h128][wh2]
    int wh = b & 1;
    int h  = (b >> 1) & 127;
    int n  = b >> 8;
    int tid = threadIdx.x;
    int wv = tid >> 6;             // 0..3
    int l  = tid & 63;

    if (tid < C_IN) {
        float sx = shifts[2 * tid] * MAX_SHIFT;
        float sy = shifts[2 * tid + 1] * MAX_SHIFT;
        float fx0 = floorf(sx), fy0 = floorf(sy);
        s_dx[tid] = (int)fx0; s_dy[tid] = (int)fy0;
        s_fx[tid] = sx - fx0;  s_fy[tid] = sy - fy0;
    }
    __syncthreads();

    const float* xn = x + (size_t)n * (C_IN * HH * WW);
    int w = wh * 64 + l;
    unsigned short* rw = row + l * RSTR;

    #pragma unroll 4
    for (int it = 0; it < 16; ++it) {
        int c = it * 4 + wv;                       // wave-uniform
        int dx = s_dx[c], dy = s_dy[c];
        float fx = s_fx[c], fy = s_fy[c];
        const float* xp = xn + (size_t)c * (HH * WW);
        int y0 = h + dy, y1 = y0 + 1;
        bool vy0 = ((unsigned)y0 < (unsigned)HH);
        bool vy1 = ((unsigned)y1 < (unsigned)HH);
        const float* r0 = xp + y0 * WW;
        const float* r1 = xp + y1 * WW;

        int x0 = w + dx, x1 = x0 + 1;
        bool vx0 = ((unsigned)x0 < (unsigned)WW);
        bool vx1 = ((unsigned)x1 < (unsigned)WW);
        float v00 = (vy0 && vx0) ? r0[x0] : 0.f;
        float v01 = (vy0 && vx1) ? r0[x1] : 0.f;
        float v10 = (vy1 && vx0) ? r1[x0] : 0.f;
        float v11 = (vy1 && vx1) ? r1[x1] : 0.f;
        float v = (1.f - fy) * ((1.f - fx) * v00 + fx * v01)
                + fy * ((1.f - fx) * v10 + fx * v11);
        float v2 = v * v, v3 = v2 * v;
        rw[c]       = bf16_rne(v);
        rw[64 + c]  = bf16_rne(v2);
        rw[128 + c] = bf16_rne(v3);
    }
    __syncthreads();

    // writeout: 64 w x 96 u32 payload = 6144 u32 ; scalar u32 lanes,
    // conflict-free LDS reads, 256B/wave coalesced global stores
    unsigned* dst = (unsigned*)(xsp + (((size_t)(n * HH + h)) * WW + wh * 64) * 192);
    const unsigned* rp = (const unsigned*)row;
    #pragma unroll
    for (int itw = 0; itw < 24; ++itw) {
        int o32 = itw * 256 + tid;        // 0..6143
        int wl = o32 / 96;
        int k4 = o32 - wl * 96;
        dst[o32] = rp[wl * (RSTR / 2) + k4];
    }
}

// =====================================================================
// weight prep for pass 2: [t9][kb6][mf4][lane64][e8] bf16
// =====================================================================
__global__ void prep_w2(const float* __restrict__ w, unsigned short* __restrict__ wbuf) {
    int id = blockIdx.x * 256 + threadIdx.x;   // < 110592
    int e = id & 7;
    int l = (id >> 3) & 63;
    int f = id >> 9;          // 0..215
    int mf = f & 3;
    int f2 = f >> 2;          // 0..53
    int kb = f2 % 6;
    int t  = f2 / 6;
    int k  = kb * 32 + (l >> 4) * 8 + e;   // 0..191
    int p  = k >> 6;
    int c  = k & 63;
    int co = mf * 16 + (l & 15);
    wbuf[id] = bf16_rne(w[(co * 192 + p * 64 + c) * 9 + t]);
}

// =====================================================================
// PASS 2: implicit-GEMM conv, pure copy staging (unchanged)
// =====================================================================
__global__ __launch_bounds__(256, 2)
void conv2(const unsigned short* __restrict__ xsp,
           const unsigned short* __restrict__ wbuf,
           const float* __restrict__ bias,
           float* __restrict__ out) {
    __shared__ unsigned short tile[612 * 40];   // [px 18x34][32k + 8 pad], 48,960 B

    int bid = blockIdx.x;
    int wg = (bid & 7) * 64 + (bid >> 3);       // bijective XCD swizzle (512 = 8*64)
    int n  = wg >> 5;
    int t5 = wg & 31;
    int i0 = (t5 >> 2) * 16;
    int j0 = (t5 & 3) * 32;

    int tid = threadIdx.x;
    int l  = tid & 63;
    int wv = tid >> 6;
    int lm = l & 15;
    int lg = l >> 4;

    f32x4 acc[4][8];
    #pragma unroll
    for (int mf = 0; mf < 4; ++mf) {
        #pragma unroll
        for (int r = 0; r < 4; ++r) {
            float bv = bias[mf * 16 + lg * 4 + r];
            #pragma unroll
            for (int nf = 0; nf < 8; ++nf) acc[mf][nf][r] = bv;
        }
    }

    const unsigned short* xn = xsp + (size_t)n * (HH * WW * 192);
    int lds_base = ((wv * 4) * 34 + lm) * 80 + lg * 16;   // bytes

    #pragma unroll 1
    for (int kb = 0; kb < 6; ++kb) {
        __syncthreads();
        // ---- stage: 612 px x 64 B (k-block) ----
        #pragma unroll
        for (int it = 0; it < 10; ++it) {
            int ch = it * 256 + tid;          // chunk id, need 2448
            if (ch < 2448) {
                int px = ch >> 2, sub = ch & 3;
                int r  = px / 34;
                int cc = px - r * 34;
                int gi = i0 - 1 + r, gj = j0 - 1 + cc;
                u32x4 d = {0, 0, 0, 0};
                if (gi >= 0 && gi < HH && gj >= 0 && gj < WW)
                    d = *(const u32x4*)(xn + ((gi * WW + gj) * 192 + kb * 32 + sub * 8));
                *(u32x4*)((char*)tile + px * 80 + sub * 16) = d;
            }
        }
        __syncthreads();

        // ---- compute: 9 taps x 8 nf x 4 mf MFMAs ----
        bf16x8 Af[4];
        #pragma unroll
        for (int mf = 0; mf < 4; ++mf)
            Af[mf] = *(const bf16x8*)(wbuf + (size_t)((0 * 6 + kb) * 4 + mf) * 512 + l * 8);

        #pragma unroll 1
        for (int t = 0; t < 9; ++t) {
            bf16x8 Afn[4];
            int tn = (t < 8) ? t + 1 : t;
            #pragma unroll
            for (int mf = 0; mf < 4; ++mf)
                Afn[mf] = *(const bf16x8*)(wbuf + (size_t)((tn * 6 + kb) * 4 + mf) * 512 + l * 8);

            int ky = t / 3, kx = t - ky * 3;
            int toff = (ky * 34 + kx) * 80;
            #pragma unroll
            for (int nf = 0; nf < 8; ++nf) {
                int rl = nf >> 1, cb = nf & 1;
                int off = lds_base + toff + (rl * 34 + cb * 16) * 80;
                bf16x8 bfrag = *(const bf16x8*)((const char*)tile + off);
                #pragma unroll
                for (int mf = 0; mf < 4; ++mf)
                    acc[mf][nf] = __builtin_amdgcn_mfma_f32_16x16x32_bf16(Af[mf], bfrag, acc[mf][nf], 0, 0, 0);
            }
            #pragma unroll
            for (int mf = 0; mf < 4; ++mf) Af[mf] = Afn[mf];
        }
    }

    // ---- epilogue ----
    #pragma unroll
    for (int mf = 0; mf < 4; ++mf) {
        #pragma unroll
        for (int nf = 0; nf < 8; ++nf) {
            int rl = nf >> 1, cb = nf & 1;
            int row = i0 + wv * 4 + rl;
            int col = j0 + cb * 16 + lm;
            #pragma unroll
            for (int r = 0; r < 4; ++r) {
                int co = mf * 16 + lg * 4 + r;
                out[((n * C_OUT + co) * HH + row) * WW + col] = acc[mf][nf][r];
            }
        }
    }
}

// =====================================================================
// Fallback tier: fused kernel (only if ws too small for xsp)
// =====================================================================
#define TH 16
#define TW 32
#define PR (TH + 2)
#define PC (TW + 2)
#define NPX (PR * PC)
#define CHP 40

__global__ void prep_w_fused(const float* __restrict__ w, unsigned short* __restrict__ wbuf) {
    int id = blockIdx.x * 256 + threadIdx.x;
    int e = id & 7;
    int l = (id >> 3) & 63;
    int frag = id >> 9;
    int mf = frag & 3;
    int f2 = frag >> 2;
    int t = f2 % 9;
    int f3 = f2 / 9;
    int p = f3 % 3;
    int kg = f3 / 3;
    int co = mf * 16 + (l & 15);
    int ci = kg * 32 + (l >> 4) * 8 + e;
    wbuf[id] = bf16_rne(w[(co * 192 + p * 64 + ci) * 9 + t]);
}

__global__ __launch_bounds__(256, 2)
void conv_fused(const float* __restrict__ x,
                const float* __restrict__ shifts,
                const unsigned short* __restrict__ wbuf,
                const float* __restrict__ bias,
                float* __restrict__ out) {
    __shared__ unsigned short tile[NPX * CHP];
    __shared__ float s_fx[C_IN], s_fy[C_IN];
    __shared__ int s_dx[C_IN], s_dy[C_IN];

    int bid = blockIdx.x;
    int wg = (bid & 7) * 64 + (bid >> 3);
    int n  = wg >> 5;
    int t5 = wg & 31;
    int i0 = (t5 >> 2) * TH;
    int j0 = (t5 & 3) * TW;

    int tid = threadIdx.x;
    int l  = tid & 63;
    int wv = tid >> 6;
    int lm = l & 15;
    int lg = l >> 4;

    if (tid < C_IN) {
        float sx = shifts[2 * tid] * MAX_SHIFT;
        float sy = shifts[2 * tid + 1] * MAX_SHIFT;
        float fx0 = floorf(sx), fy0 = floorf(sy);
        s_dx[tid] = (int)fx0; s_dy[tid] = (int)fy0;
        s_fx[tid] = sx - fx0;  s_fy[tid] = sy - fy0;
    }

    f32x4 acc[4][8];
    #pragma unroll
    for (int mf = 0; mf < 4; ++mf) {
        #pragma unroll
        for (int r = 0; r < 4; ++r) {
            float b = bias[mf * 16 + lg * 4 + r];
            #pragma unroll
            for (int nf = 0; nf < 8; ++nf) acc[mf][nf][r] = b;
        }
    }

    const float* xn = x + n * (C_IN * HH * WW);
    const char* ldsb = (const char*)tile;
    int lds_base = ((wv * 4) * PC + lm) * (CHP * 2) + lg * 16;

    #pragma unroll 1
    for (int kg = 0; kg < 2; ++kg) {
        __syncthreads();
        for (int e = tid; e < NPX * 32; e += 256) {
            int cl = e / NPX;
            int px = e - cl * NPX;
            int r  = px / PC;
            int c  = px - r * PC;
            int ci = kg * 32 + cl;
            int gi = i0 - 1 + r;
            int gj = j0 - 1 + c;
            float v = 0.f;
            if (gi >= 0 && gi < HH && gj >= 0 && gj < WW) {
                int y0 = gi + s_dy[ci], y1 = y0 + 1;
                int x0 = gj + s_dx[ci], x1 = x0 + 1;
                float fx = s_fx[ci], fy = s_fy[ci];
                const float* xp = xn + ci * (HH * WW);
                float v00 = (y0 >= 0 && y0 < HH && x0 >= 0 && x0 < WW) ? xp[y0 * WW + x0] : 0.f;
                float v01 = (y0 >= 0 && y0 < HH && x1 >= 0 && x1 < WW) ? xp[y0 * WW + x1] : 0.f;
                float v10 = (y1 >= 0 && y1 < HH && x0 >= 0 && x0 < WW) ? xp[y1 * WW + x0] : 0.f;
                float v11 = (y1 >= 0 && y1 < HH && x1 >= 0 && x1 < WW) ? xp[y1 * WW + x1] : 0.f;
                v = (1.f - fy) * ((1.f - fx) * v00 + fx * v01)
                  + fy * ((1.f - fx) * v10 + fx * v11);
            }
            tile[px * CHP + cl] = bf16_rne(v);
        }
        __syncthreads();

        const unsigned short* wk = wbuf + kg * (3 * 9 * 4 * 512);
        #pragma unroll 1
        for (int t = 0; t < 9; ++t) {
            int ky = t / 3, kx = t - ky * 3;
            bf16x8 Af[3][4];
            #pragma unroll
            for (int p = 0; p < 3; ++p)
                #pragma unroll
                for (int mf = 0; mf < 4; ++mf)
                    Af[p][mf] = *(const bf16x8*)(wk + ((size_t)((p * 9 + t) * 4 + mf)) * 512 + l * 8);

            int toff = (ky * PC + kx) * (CHP * 2);
            #pragma unroll
            for (int nf = 0; nf < 8; ++nf) {
                int rl = nf >> 1, cb = nf & 1;
                int off = lds_base + toff + (rl * PC + cb * 16) * (CHP * 2);
                bf16x8 b1 = *(const bf16x8*)(ldsb + off);
                u32x4 bu = __builtin_bit_cast(u32x4, b1);
                unsigned d2[4], d3[4];
                #pragma unroll
                for (int q = 0; q < 4; ++q) {
                    float fl = __builtin_bit_cast(float, bu[q] << 16);
                    float fh = __builtin_bit_cast(float, bu[q] & 0xffff0000u);
                    float fl2 = fl * fl, fh2 = fh * fh;
                    float fl3 = fl2 * fl, fh3 = fh2 * fh;
                    d2[q] = pack_bf16x2(fl2, fh2);
                    d3[q] = pack_bf16x2(fl3, fh3);
                }
                bf16x8 b2 = __builtin_bit_cast(bf16x8, (u32x4){d2[0], d2[1], d2[2], d2[3]});
                bf16x8 b3 = __builtin_bit_cast(bf16x8, (u32x4){d3[0], d3[1], d3[2], d3[3]});
                #pragma unroll
                for (int mf = 0; mf < 4; ++mf)
                    acc[mf][nf] = __builtin_amdgcn_mfma_f32_16x16x32_bf16(Af[0][mf], b1, acc[mf][nf], 0, 0, 0);
                #pragma unroll
                for (int mf = 0; mf < 4; ++mf)
                    acc[mf][nf] = __builtin_amdgcn_mfma_f32_16x16x32_bf16(Af[1][mf], b2, acc[mf][nf], 0, 0, 0);
                #pragma unroll
                for (int mf = 0; mf < 4; ++mf)
                    acc[mf][nf] = __builtin_amdgcn_mfma_f32_16x16x32_bf16(Af[2][mf], b3, acc[mf][nf], 0, 0, 0);
            }
        }
    }

    #pragma unroll
    for (int mf = 0; mf < 4; ++mf) {
        #pragma unroll
        for (int nf = 0; nf < 8; ++nf) {
            int rl = nf >> 1, cb = nf & 1;
            int row = i0 + wv * 4 + rl;
            int col = j0 + cb * 16 + lm;
            #pragma unroll
            for (int r = 0; r < 4; ++r) {
                int co = mf * 16 + lg * 4 + r;
                out[((n * C_OUT + co) * HH + row) * WW + col] = acc[mf][nf][r];
            }
        }
    }
}

extern "C" void kernel_launch(void* const* d_in, const int* in_sizes, int n_in,
                              void* d_out, int out_size, void* d_ws, size_t ws_size,
                              hipStream_t stream) {
    (void)in_sizes; (void)n_in; (void)out_size;
    const float* x      = (const float*)d_in[0];
    const float* weight = (const float*)d_in[1];
    const float* bias   = (const float*)d_in[2];
    const float* shifts = (const float*)d_in[3];
    float* out = (float*)d_out;

    const size_t xsp_elems = (size_t)NB * HH * WW * 192;        // u16 count
    const size_t need2 = xsp_elems * 2 + 110592 * 2;            // ~100.9 MB
    const size_t need1 = 110592 * 2;                            // 216 KB

    if (ws_size >= need2) {
        unsigned short* xsp  = (unsigned short*)d_ws;
        unsigned short* wbuf = xsp + xsp_elems;
        prep_w2<<<432, 256, 0, stream>>>(weight, wbuf);
        shift_pow<<<NB * HH * 2, 256, 0, stream>>>(x, shifts, xsp);
        conv2<<<512, 256, 0, stream>>>(xsp, wbuf, bias, out);
    } else {
        unsigned short* wbuf = (unsigned short*)d_ws;
        prep_w_fused<<<432, 256, 0, stream>>>(weight, wbuf);
        conv_fused<<<512, 256, 0, stream>>>(x, shifts, wbuf, bias, out);
    }
}

// Round 7
// 107.541 us; speedup vs baseline: 14.4286x; 1.0622x over previous
//
#include <hip/hip_runtime.h>
#include <hip/hip_bf16.h>
#include <math.h>

#define NB 16
#define C_IN 64
#define C_OUT 64
#define HH 128
#define WW 128
#define MAX_SHIFT 4.0f

typedef __attribute__((ext_vector_type(8))) short bf16x8;
typedef __attribute__((ext_vector_type(4))) float f32x4;
typedef __attribute__((ext_vector_type(4))) unsigned int u32x4;

__device__ inline unsigned short bf16_rne(float f) {
    unsigned u = __builtin_bit_cast(unsigned, f);
    u += 0x7fffu + ((u >> 16) & 1u);
    return (unsigned short)(u >> 16);
}
__device__ inline unsigned pack_bf16x2(float lo, float hi) {
    unsigned ul = __builtin_bit_cast(unsigned, lo);
    unsigned uh = __builtin_bit_cast(unsigned, hi);
    ul += 0x7fffu + ((ul >> 16) & 1u);
    uh += 0x7fffu + ((uh >> 16) & 1u);
    return (ul >> 16) | (uh & 0xffff0000u);
}

// =====================================================================
// PASS 1: bilinear shift + powers -> xsp[kb6][n][h][w][32] bf16
//   k = p*64 + c ; region kb holds k in [kb*32, kb*32+32)
// =====================================================================
#define RSTR 202   // u16 stride per w in LDS (odd dword stride 101 -> conflict-free)

__global__ __launch_bounds__(256)
void shift_pow(const float* __restrict__ x, const float* __restrict__ shifts,
               unsigned short* __restrict__ xsp) {
    __shared__ unsigned short row[64 * RSTR];   // 25,856 B
    __shared__ float s_fx[C_IN], s_fy[C_IN];
    __shared__ int s_dx[C_IN], s_dy[C_IN];

    int b = blockIdx.x;            // [n16][h128][wh2]
    int wh = b & 1;
    int h  = (b >> 1) & 127;
    int n  = b >> 8;
    int tid = threadIdx.x;
    int wv = tid >> 6;             // 0..3
    int l  = tid & 63;

    if (tid < C_IN) {
        float sx = shifts[2 * tid] * MAX_SHIFT;
        float sy = shifts[2 * tid + 1] * MAX_SHIFT;
        float fx0 = floorf(sx), fy0 = floorf(sy);
        s_dx[tid] = (int)fx0; s_dy[tid] = (int)fy0;
        s_fx[tid] = sx - fx0;  s_fy[tid] = sy - fy0;
    }
    __syncthreads();

    const float* xn = x + (size_t)n * (C_IN * HH * WW);
    int w = wh * 64 + l;
    unsigned short* rw = row + l * RSTR;

    #pragma unroll 8
    for (int it = 0; it < 16; ++it) {
        int c = it * 4 + wv;                       // wave-uniform
        int dx = s_dx[c], dy = s_dy[c];
        float fx = s_fx[c], fy = s_fy[c];
        const float* xp = xn + (size_t)c * (HH * WW);
        int y0 = h + dy, y1 = y0 + 1;
        bool vy0 = ((unsigned)y0 < (unsigned)HH);
        bool vy1 = ((unsigned)y1 < (unsigned)HH);
        const float* r0 = xp + y0 * WW;
        const float* r1 = xp + y1 * WW;

        int x0 = w + dx, x1 = x0 + 1;
        bool vx0 = ((unsigned)x0 < (unsigned)WW);
        bool vx1 = ((unsigned)x1 < (unsigned)WW);
        float v00 = (vy0 && vx0) ? r0[x0] : 0.f;
        float v01 = (vy0 && vx1) ? r0[x1] : 0.f;
        float v10 = (vy1 && vx0) ? r1[x0] : 0.f;
        float v11 = (vy1 && vx1) ? r1[x1] : 0.f;
        float v = (1.f - fy) * ((1.f - fx) * v00 + fx * v01)
                + fy * ((1.f - fx) * v10 + fx * v11);
        float v2 = v * v, v3 = v2 * v;
        rw[c]       = bf16_rne(v);
        rw[64 + c]  = bf16_rne(v2);
        rw[128 + c] = bf16_rne(v3);
    }
    __syncthreads();

    // writeout: 6 regions x (64 w x 16 u32) = 6 x 4KB contiguous
    const unsigned* rp = (const unsigned*)row;
    unsigned* xsp32 = (unsigned*)xsp;
    #pragma unroll 1
    for (int kb = 0; kb < 6; ++kb) {
        unsigned* dst = xsp32 + ((size_t)(kb * NB + n) * (HH * WW) + (size_t)h * WW + wh * 64) * 16;
        #pragma unroll
        for (int itw = 0; itw < 4; ++itw) {
            int o32 = itw * 256 + tid;        // 0..1023
            int wl = o32 >> 4;
            int k4 = o32 & 15;
            dst[o32] = rp[wl * (RSTR / 2) + kb * 16 + k4];
        }
    }
}

// =====================================================================
// weight prep: [t9][kb6][mf4][lane64][e8] bf16
// =====================================================================
__global__ void prep_w2(const float* __restrict__ w, unsigned short* __restrict__ wbuf) {
    int id = blockIdx.x * 256 + threadIdx.x;   // < 110592
    int e = id & 7;
    int l = (id >> 3) & 63;
    int f = id >> 9;          // 0..215
    int mf = f & 3;
    int f2 = f >> 2;          // 0..53
    int kb = f2 % 6;
    int t  = f2 / 6;
    int k  = kb * 32 + (l >> 4) * 8 + e;   // 0..191
    int p  = k >> 6;
    int c  = k & 63;
    int co = mf * 16 + (l & 15);
    wbuf[id] = bf16_rne(w[(co * 192 + p * 64 + c) * 9 + t]);
}

// =====================================================================
// PASS 2: implicit-GEMM conv. 16x16 output tile, grid 1024.
//   LDS tile [18*18 px][44 u16] (88B stride -> conflict-free b128 reads)
// =====================================================================
#define CSTR 44    // u16 per px (32 payload + 12 pad); 88 B

__global__ __launch_bounds__(256, 2)
void conv2(const unsigned short* __restrict__ xsp,
           const unsigned short* __restrict__ wbuf,
           const float* __restrict__ bias,
           float* __restrict__ out) {
    __shared__ unsigned short tile[324 * CSTR];   // 28,512 B

    int bid = blockIdx.x;
    int wg = (bid & 7) * 128 + (bid >> 3);   // bijective XCD swizzle (1024 = 8*128)
    int n  = wg >> 6;
    int t6 = wg & 63;
    int i0 = (t6 >> 3) * 16;
    int j0 = (t6 & 7) * 16;

    int tid = threadIdx.x;
    int l  = tid & 63;
    int wv = tid >> 6;
    int lm = l & 15;
    int lg = l >> 4;

    f32x4 acc[4][4];      // [mf][rl]
    #pragma unroll
    for (int mf = 0; mf < 4; ++mf) {
        #pragma unroll
        for (int r = 0; r < 4; ++r) {
            float bv = bias[mf * 16 + lg * 4 + r];
            #pragma unroll
            for (int nf = 0; nf < 4; ++nf) acc[mf][nf][r] = bv;
        }
    }

    int lds_base = (wv * 4 * 18 + lm) * 88 + lg * 16;   // bytes

    #pragma unroll 1
    for (int kb = 0; kb < 6; ++kb) {
        const unsigned short* xr = xsp + (size_t)(kb * NB + n) * (HH * WW * 32);
        __syncthreads();
        // ---- stage: 18 rows x 18 px x 64 B ; contiguous 1152B runs per row ----
        #pragma unroll
        for (int it = 0; it < 6; ++it) {
            int ch = it * 256 + tid;          // 0..1295 (18*18*4)
            if (ch < 1296) {
                int rr  = ch / 72;
                int rem = ch - rr * 72;
                int pxr = rem >> 2, sub = rem & 3;
                int gi = i0 - 1 + rr, gj = j0 - 1 + pxr;
                u32x4 d = {0, 0, 0, 0};
                if ((unsigned)gi < (unsigned)HH && (unsigned)gj < (unsigned)WW)
                    d = *(const u32x4*)(xr + ((size_t)gi * WW + gj) * 32 + sub * 8);
                *(u32x4*)((char*)tile + (rr * 18 + pxr) * 88 + sub * 16) = d;
            }
        }
        __syncthreads();

        // ---- compute: 9 taps x 4 nf x 4 mf MFMAs ----
        bf16x8 Af[4];
        #pragma unroll
        for (int mf = 0; mf < 4; ++mf)
            Af[mf] = *(const bf16x8*)(wbuf + (size_t)((0 * 6 + kb) * 4 + mf) * 512 + l * 8);

        #pragma unroll 1
        for (int t = 0; t < 9; ++t) {
            bf16x8 Afn[4];
            int tn = (t < 8) ? t + 1 : t;
            #pragma unroll
            for (int mf = 0; mf < 4; ++mf)
                Afn[mf] = *(const bf16x8*)(wbuf + (size_t)((tn * 6 + kb) * 4 + mf) * 512 + l * 8);

            int ky = t / 3, kx = t - ky * 3;
            #pragma unroll
            for (int nf = 0; nf < 4; ++nf) {
                int off = lds_base + ((nf + ky) * 18 + kx) * 88;
                bf16x8 bfrag = *(const bf16x8*)((const char*)tile + off);
                #pragma unroll
                for (int mf = 0; mf < 4; ++mf)
                    acc[mf][nf] = __builtin_amdgcn_mfma_f32_16x16x32_bf16(Af[mf], bfrag, acc[mf][nf], 0, 0, 0);
            }
            #pragma unroll
            for (int mf = 0; mf < 4; ++mf) Af[mf] = Afn[mf];
        }
    }

    // ---- epilogue ----
    #pragma unroll
    for (int mf = 0; mf < 4; ++mf) {
        #pragma unroll
        for (int nf = 0; nf < 4; ++nf) {
            int rowi = i0 + wv * 4 + nf;
            int col = j0 + lm;
            #pragma unroll
            for (int r = 0; r < 4; ++r) {
                int co = mf * 16 + lg * 4 + r;
                out[(((size_t)n * C_OUT + co) * HH + rowi) * WW + col] = acc[mf][nf][r];
            }
        }
    }
}

// =====================================================================
// Fallback tier: fused kernel (only if ws too small for xsp)
// =====================================================================
#define TH 16
#define TW 32
#define PR (TH + 2)
#define PC (TW + 2)
#define NPX (PR * PC)
#define CHP 40

__global__ void prep_w_fused(const float* __restrict__ w, unsigned short* __restrict__ wbuf) {
    int id = blockIdx.x * 256 + threadIdx.x;
    int e = id & 7;
    int l = (id >> 3) & 63;
    int frag = id >> 9;
    int mf = frag & 3;
    int f2 = frag >> 2;
    int t = f2 % 9;
    int f3 = f2 / 9;
    int p = f3 % 3;
    int kg = f3 / 3;
    int co = mf * 16 + (l & 15);
    int ci = kg * 32 + (l >> 4) * 8 + e;
    wbuf[id] = bf16_rne(w[(co * 192 + p * 64 + ci) * 9 + t]);
}

__global__ __launch_bounds__(256, 2)
void conv_fused(const float* __restrict__ x,
                const float* __restrict__ shifts,
                const unsigned short* __restrict__ wbuf,
                const float* __restrict__ bias,
                float* __restrict__ out) {
    __shared__ unsigned short tile[NPX * CHP];
    __shared__ float s_fx[C_IN], s_fy[C_IN];
    __shared__ int s_dx[C_IN], s_dy[C_IN];

    int bid = blockIdx.x;
    int wg = (bid & 7) * 64 + (bid >> 3);
    int n  = wg >> 5;
    int t5 = wg & 31;
    int i0 = (t5 >> 2) * TH;
    int j0 = (t5 & 3) * TW;

    int tid = threadIdx.x;
    int l  = tid & 63;
    int wv = tid >> 6;
    int lm = l & 15;
    int lg = l >> 4;

    if (tid < C_IN) {
        float sx = shifts[2 * tid] * MAX_SHIFT;
        float sy = shifts[2 * tid + 1] * MAX_SHIFT;
        float fx0 = floorf(sx), fy0 = floorf(sy);
        s_dx[tid] = (int)fx0; s_dy[tid] = (int)fy0;
        s_fx[tid] = sx - fx0;  s_fy[tid] = sy - fy0;
    }

    f32x4 acc[4][8];
    #pragma unroll
    for (int mf = 0; mf < 4; ++mf) {
        #pragma unroll
        for (int r = 0; r < 4; ++r) {
            float b = bias[mf * 16 + lg * 4 + r];
            #pragma unroll
            for (int nf = 0; nf < 8; ++nf) acc[mf][nf][r] = b;
        }
    }

    const float* xn = x + n * (C_IN * HH * WW);
    const char* ldsb = (const char*)tile;
    int lds_base = ((wv * 4) * PC + lm) * (CHP * 2) + lg * 16;

    #pragma unroll 1
    for (int kg = 0; kg < 2; ++kg) {
        __syncthreads();
        for (int e = tid; e < NPX * 32; e += 256) {
            int cl = e / NPX;
            int px = e - cl * NPX;
            int r  = px / PC;
            int c  = px - r * PC;
            int ci = kg * 32 + cl;
            int gi = i0 - 1 + r;
            int gj = j0 - 1 + c;
            float v = 0.f;
            if (gi >= 0 && gi < HH && gj >= 0 && gj < WW) {
                int y0 = gi + s_dy[ci], y1 = y0 + 1;
                int x0 = gj + s_dx[ci], x1 = x0 + 1;
                float fx = s_fx[ci], fy = s_fy[ci];
                const float* xp = xn + ci * (HH * WW);
                float v00 = (y0 >= 0 && y0 < HH && x0 >= 0 && x0 < WW) ? xp[y0 * WW + x0] : 0.f;
                float v01 = (y0 >= 0 && y0 < HH && x1 >= 0 && x1 < WW) ? xp[y0 * WW + x1] : 0.f;
                float v10 = (y1 >= 0 && y1 < HH && x0 >= 0 && x0 < WW) ? xp[y1 * WW + x0] : 0.f;
                float v11 = (y1 >= 0 && y1 < HH && x1 >= 0 && x1 < WW) ? xp[y1 * WW + x1] : 0.f;
                v = (1.f - fy) * ((1.f - fx) * v00 + fx * v01)
                  + fy * ((1.f - fx) * v10 + fx * v11);
            }
            tile[px * CHP + cl] = bf16_rne(v);
        }
        __syncthreads();

        const unsigned short* wk = wbuf + kg * (3 * 9 * 4 * 512);
        #pragma unroll 1
        for (int t = 0; t < 9; ++t) {
            int ky = t / 3, kx = t - ky * 3;
            bf16x8 Af[3][4];
            #pragma unroll
            for (int p = 0; p < 3; ++p)
                #pragma unroll
                for (int mf = 0; mf < 4; ++mf)
                    Af[p][mf] = *(const bf16x8*)(wk + ((size_t)((p * 9 + t) * 4 + mf)) * 512 + l * 8);

            int toff = (ky * PC + kx) * (CHP * 2);
            #pragma unroll
            for (int nf = 0; nf < 8; ++nf) {
                int rl = nf >> 1, cb = nf & 1;
                int off = lds_base + toff + (rl * PC + cb * 16) * (CHP * 2);
                bf16x8 b1 = *(const bf16x8*)(ldsb + off);
                u32x4 bu = __builtin_bit_cast(u32x4, b1);
                unsigned d2[4], d3[4];
                #pragma unroll
                for (int q = 0; q < 4; ++q) {
                    float fl = __builtin_bit_cast(float, bu[q] << 16);
                    float fh = __builtin_bit_cast(float, bu[q] & 0xffff0000u);
                    float fl2 = fl * fl, fh2 = fh * fh;
                    float fl3 = fl2 * fl, fh3 = fh2 * fh;
                    d2[q] = pack_bf16x2(fl2, fh2);
                    d3[q] = pack_bf16x2(fl3, fh3);
                }
                bf16x8 b2 = __builtin_bit_cast(bf16x8, (u32x4){d2[0], d2[1], d2[2], d2[3]});
                bf16x8 b3 = __builtin_bit_cast(bf16x8, (u32x4){d3[0], d3[1], d3[2], d3[3]});
                #pragma unroll
                for (int mf = 0; mf < 4; ++mf)
                    acc[mf][nf] = __builtin_amdgcn_mfma_f32_16x16x32_bf16(Af[0][mf], b1, acc[mf][nf], 0, 0, 0);
                #pragma unroll
                for (int mf = 0; mf < 4; ++mf)
                    acc[mf][nf] = __builtin_amdgcn_mfma_f32_16x16x32_bf16(Af[1][mf], b2, acc[mf][nf], 0, 0, 0);
                #pragma unroll
                for (int mf = 0; mf < 4; ++mf)
                    acc[mf][nf] = __builtin_amdgcn_mfma_f32_16x16x32_bf16(Af[2][mf], b3, acc[mf][nf], 0, 0, 0);
            }
        }
    }

    #pragma unroll
    for (int mf = 0; mf < 4; ++mf) {
        #pragma unroll
        for (int nf = 0; nf < 8; ++nf) {
            int rl = nf >> 1, cb = nf & 1;
            int row = i0 + wv * 4 + rl;
            int col = j0 + cb * 16 + lm;
            #pragma unroll
            for (int r = 0; r < 4; ++r) {
                int co = mf * 16 + lg * 4 + r;
                out[((n * C_OUT + co) * HH + row) * WW + col] = acc[mf][nf][r];
            }
        }
    }
}

extern "C" void kernel_launch(void* const* d_in, const int* in_sizes, int n_in,
                              void* d_out, int out_size, void* d_ws, size_t ws_size,
                              hipStream_t stream) {
    (void)in_sizes; (void)n_in; (void)out_size;
    const float* x      = (const float*)d_in[0];
    const float* weight = (const float*)d_in[1];
    const float* bias   = (const float*)d_in[2];
    const float* shifts = (const float*)d_in[3];
    float* out = (float*)d_out;

    const size_t xsp_elems = (size_t)NB * HH * WW * 192;        // u16 count
    const size_t need2 = xsp_elems * 2 + 110592 * 2;            // ~100.9 MB
    const size_t need1 = 110592 * 2;                            // 216 KB

    if (ws_size >= need2) {
        unsigned short* xsp  = (unsigned short*)d_ws;
        unsigned short* wbuf = xsp + xsp_elems;
        prep_w2<<<432, 256, 0, stream>>>(weight, wbuf);
        shift_pow<<<NB * HH * 2, 256, 0, stream>>>(x, shifts, xsp);
        conv2<<<1024, 256, 0, stream>>>(xsp, wbuf, bias, out);
    } else {
        unsigned short* wbuf = (unsigned short*)d_ws;
        prep_w_fused<<<432, 256, 0, stream>>>(weight, wbuf);
        conv_fused<<<NB * 4 * 4, 256, 0, stream>>>(x, shifts, wbuf, bias, out);
    }
}